// Round 6
// baseline (891.117 us; speedup 1.0000x reference)
//
#include <hip/hip_runtime.h>
#include <cstddef>

#define NB 64
#define NP 1024
#define NPTS (NB * NP)
#define NETBLOCKS 512

typedef __attribute__((ext_vector_type(8))) short v8s;
typedef __attribute__((ext_vector_type(4))) float f32x4;

__device__ __forceinline__ float dist2(const float4 pi, const float sqi, const float4 pq) {
    const float dot = fmaf(pi.z, pq.z, fmaf(pi.y, pq.y, pi.x * pq.x));
    return fmaf(-2.0f, dot, sqi + pq.w);
}

__device__ __forceinline__ void pack8(const float* w, v8s& hv, v8s& lv) {
    union { v8s v; unsigned int u[4]; } H, L;
#pragma unroll
    for (int p = 0; p < 4; ++p) {
        unsigned int a = __float_as_uint(w[2 * p]);
        unsigned int b = __float_as_uint(w[2 * p + 1]);
        unsigned int ha = a & 0xffff0000u, hb = b & 0xffff0000u;
        H.u[p] = (ha >> 16) | hb;
        float la = w[2 * p] - __uint_as_float(ha);
        float lb = w[2 * p + 1] - __uint_as_float(hb);
        L.u[p] = (__float_as_uint(la) >> 16) | (__float_as_uint(lb) & 0xffff0000u);
    }
    hv = H.v; lv = L.v;
}

// ---- shared helpers for the edge phases -----------------------------------

// V-rows of one tile into registers; duplicate-k slots reuse the k=0 row.
template <int PT, int KP, int KREAL>
__device__ __forceinline__ void load_vrows(const float* __restrict__ V,
                                           int idxa, int idxb, int tt, int lane,
                                           float vbuf[16])
{
    constexpr int KSH = (KP == 8) ? 3 : 2;
#pragma unroll
    for (int e = 0; e < 16; ++e) {
        const int p = e >> KSH;
        const int k = e & (KP - 1);
        if (k >= KREAL) continue;
        const int li = (tt * PT + p) * 6 + k;
        const int j = (li < 64) ? __builtin_amdgcn_readlane(idxa, li)
                                : __builtin_amdgcn_readlane(idxb, li - 64);
        vbuf[e] = V[(size_t)j * 64 + lane];
    }
#pragma unroll
    for (int e = 0; e < 16; ++e) {
        const int p = e >> KSH;
        const int k = e & (KP - 1);
        if (k >= KREAL) vbuf[e] = vbuf[p << KSH];
    }
}

template <int PT>
__device__ __forceinline__ void load_urows(const float* __restrict__ U, int pb0,
                                           int tt, int lane, float ubuf[PT])
{
#pragma unroll
    for (int p = 0; p < PT; ++p)
        ubuf[p] = U[(size_t)(pb0 + tt * PT + p) * 64 + lane];
}

// stage relu(u+v) hi/lo bf16 rows into wave-private LDS, then 24 MFMA.
template <int KSH>
__device__ __forceinline__ void stage_mfma(char* base, int lane,
                                           const float vbuf[16], const float ubuf[],
                                           const v8s bh[4][2], const v8s bl[4][2],
                                           f32x4 acc[4])
{
#pragma unroll
    for (int e = 0; e < 16; ++e) {
        const int p = e >> KSH;
        float tv = ubuf[p] + vbuf[e];
        tv = fmaxf(tv, 0.0f);
        const unsigned int tu = __float_as_uint(tv);
        const unsigned int hi = tu & 0xffff0000u;
        const float lo = tv - __uint_as_float(hi);
        *((short*)(base + e * 272) + lane)       = (short)(hi >> 16);
        *((short*)(base + e * 272 + 128) + lane) = (short)(__float_as_uint(lo) >> 16);
    }
    __builtin_amdgcn_wave_barrier();
    __builtin_amdgcn_s_waitcnt(0xc07f);   // lgkmcnt(0): ds_writes visible

    v8s ah[2], al[2];
#pragma unroll
    for (int ks = 0; ks < 2; ++ks) {
        ah[ks] = *(const v8s*)(base + (lane & 15) * 272 + ks * 64 + (lane >> 4) * 16);
        al[ks] = *(const v8s*)(base + (lane & 15) * 272 + 128 + ks * 64 + (lane >> 4) * 16);
    }
#pragma unroll
    for (int nt = 0; nt < 4; ++nt) acc[nt] = (f32x4){0.f, 0.f, 0.f, 0.f};
#pragma unroll
    for (int nt = 0; nt < 4; ++nt) {
#pragma unroll
        for (int ks = 0; ks < 2; ++ks) {
            acc[nt] = __builtin_amdgcn_mfma_f32_16x16x32_bf16(ah[ks], bh[nt][ks], acc[nt], 0, 0, 0);
            acc[nt] = __builtin_amdgcn_mfma_f32_16x16x32_bf16(ah[ks], bl[nt][ks], acc[nt], 0, 0, 0);
            acc[nt] = __builtin_amdgcn_mfma_f32_16x16x32_bf16(al[ks], bh[nt][ks], acc[nt], 0, 0, 0);
        }
    }
}

// ---------------------------------------------------------------------------
// Kernel 1: proven top-6 kNN + fused layer-1 prep tail.  Block 0 also zeroes
// pooled and the net_kernel barrier counters (kernel-boundary coherence makes
// them safely visible to the following launch).
// ---------------------------------------------------------------------------
__global__ __launch_bounds__(256) void knn6_prep_kernel(
    const float* __restrict__ pos,
    const float* __restrict__ W1, const float* __restrict__ b1,
    int* __restrict__ idx,
    float* __restrict__ Uout, float* __restrict__ Vout,
    float* __restrict__ pooled, unsigned* __restrict__ bar)
{
    __shared__ float4 pts[NP];
    __shared__ float  sd[256 * 4];
    __shared__ float  thr[64];
    __shared__ int    ci[256 * 8];
    __shared__ int    cn[256];

    const int blk = blockIdx.x;
    const int b = blk >> 4;
    const int chunk = blk & 15;
    const int t = threadIdx.x;

    if (blk == 0) {
#pragma unroll
        for (int i = 0; i < 16; ++i) pooled[i * 256 + t] = 0.0f;
        if (t < 8) bar[t] = 0u;
    }

    const float* gp = pos + (size_t)b * NP * 3;
    for (int q = t; q < NP; q += 256) {
        float x = gp[q * 3 + 0], y = gp[q * 3 + 1], z = gp[q * 3 + 2];
        pts[q] = make_float4(x, y, z, x * x + y * y + z * z);
    }
    __syncthreads();

    const int p = t >> 2;
    const int sub = t & 3;
    const int il = chunk * 64 + p;
    const float4 pi = pts[il];
    const float sqi = pi.w;

    float d0 = 1e30f, d1 = 1e30f, d2v = 1e30f, d3 = 1e30f;
#pragma unroll 4
    for (int it = 0; it < 256; ++it) {
        const int q = (it << 2) | sub;
        const float dq = dist2(pi, sqi, pts[q]);
        d3  = __builtin_amdgcn_fmed3f(dq, d2v, d3);
        d2v = __builtin_amdgcn_fmed3f(dq, d1, d2v);
        d1  = __builtin_amdgcn_fmed3f(dq, d0, d1);
        d0  = fminf(dq, d0);
    }
    {
        float* sp = &sd[t * 4];
        sp[0] = d0; sp[1] = d1; sp[2] = d2v; sp[3] = d3;
    }
    __syncthreads();

    if (t < 64) {
        float e0 = 1e30f, e1 = 1e30f, e2 = 1e30f, e3 = 1e30f, e4 = 1e30f, e5 = 1e30f;
#pragma unroll
        for (int s = 0; s < 4; ++s) {
            const float* q4 = &sd[(t * 4 + s) * 4];
#pragma unroll
            for (int k = 0; k < 4; ++k) {
                const float d = q4[k];
                e5 = __builtin_amdgcn_fmed3f(d, e4, e5);
                e4 = __builtin_amdgcn_fmed3f(d, e3, e4);
                e3 = __builtin_amdgcn_fmed3f(d, e2, e3);
                e2 = __builtin_amdgcn_fmed3f(d, e1, e2);
                e1 = __builtin_amdgcn_fmed3f(d, e0, e1);
                e0 = fminf(d, e0);
            }
        }
        thr[t] = e5;
    }
    __syncthreads();

    const float th = thr[p];
    int cnt = 0;
#pragma unroll 4
    for (int it = 0; it < 256; ++it) {
        const int q = (it << 2) | sub;
        const float dq = dist2(pi, sqi, pts[q]);
        if (dq <= th) {
            ci[t * 8 + (cnt & 7)] = q;
            ++cnt;
        }
    }
    cn[t] = (cnt > 8) ? 8 : cnt;
    __syncthreads();

    if (t < 64) {
        const float4 pit = pts[chunk * 64 + t];
        const float sqit = pit.w;
        float e0 = 1e30f, e1 = 1e30f, e2 = 1e30f, e3 = 1e30f, e4 = 1e30f, e5 = 1e30f;
        int j0 = 0x7fffffff, j1 = 0x7fffffff, j2 = 0x7fffffff,
            j3 = 0x7fffffff, j4 = 0x7fffffff, j5 = 0x7fffffff;
#pragma unroll
        for (int s = 0; s < 4; ++s) {
            const int tid = t * 4 + s;
            const int n = cn[tid];
            for (int e = 0; e < n; ++e) {
                const int q = ci[tid * 8 + e];
                const float d = dist2(pit, sqit, pts[q]);
                if (d < e5 || (d == e5 && q < j5)) {
                    if (d < e4 || (d == e4 && q < j4)) {
                        e5 = e4; j5 = j4;
                        if (d < e3 || (d == e3 && q < j3)) {
                            e4 = e3; j4 = j3;
                            if (d < e2 || (d == e2 && q < j2)) {
                                e3 = e2; j3 = j2;
                                if (d < e1 || (d == e1 && q < j1)) {
                                    e2 = e1; j2 = j1;
                                    if (d < e0 || (d == e0 && q < j0)) {
                                        e1 = e0; j1 = j0; e0 = d; j0 = q;
                                    } else { e1 = d; j1 = q; }
                                } else { e2 = d; j2 = q; }
                            } else { e3 = d; j3 = q; }
                        } else { e4 = d; j4 = q; }
                    } else { e5 = d; j5 = q; }
                }
            }
        }
        const int gb = b * NP;
        int* op = idx + (size_t)(gb + chunk * 64 + t) * 6;
        op[0] = gb + j0; op[1] = gb + j1; op[2] = gb + j2;
        op[3] = gb + j3; op[4] = gb + j4; op[5] = gb + j5;
    }

    // ---- fused prep tail: 64 points x 64 channels (16 per thread) ---------
    {
        const int p2 = t >> 2;
        const int cb = (t & 3) * 16;
        const int il2 = chunk * 64 + p2;
        const float4 pp = pts[il2];
        const size_t gi = (size_t)(b * NP + il2) * 64;
#pragma unroll
        for (int cc = 0; cc < 16; ++cc) {
            const int c = cb + cc;
            float u = b1[c];
            u = fmaf(pp.x, W1[0 * 64 + c] - W1[6 * 64 + c], u);
            u = fmaf(pp.y, W1[1 * 64 + c] - W1[7 * 64 + c], u);
            u = fmaf(pp.z, W1[2 * 64 + c] - W1[8 * 64 + c], u);
            Uout[gi + c] = u;
            float v =      pp.x * (W1[3 * 64 + c] + W1[6 * 64 + c]);
            v = fmaf(pp.y, W1[4 * 64 + c] + W1[7 * 64 + c], v);
            v = fmaf(pp.z, W1[5 * 64 + c] + W1[8 * 64 + c], v);
            Vout[gi + c] = v;
        }
    }
}

// ---------------------------------------------------------------------------
// Phase: fused edge(N) + uv(N+1)  (round-5 verified math, single-buffered).
// ---------------------------------------------------------------------------
template <int PT, int KP, int KREAL>
__device__ __forceinline__ void edge_uv_phase(
    const float* __restrict__ U, const float* __restrict__ V,
    const int idxa, const int idxb,
    const float* __restrict__ W2, const float* __restrict__ b2,
    const float* __restrict__ W1n, const float* __restrict__ b1n,
    const float* __restrict__ pos,
    float* __restrict__ Uout, float* __restrict__ Vout,
    char* base, float* hw, const int lane, const int col, const int quad,
    const int base16)
{
    constexpr int KSH = (KP == 8) ? 3 : 2;
    constexpr int TPW = 16 / PT;

    {
        v8s bh[4][2], bl[4][2];
#pragma unroll
        for (int nt = 0; nt < 4; ++nt) {
#pragma unroll
            for (int ks = 0; ks < 2; ++ks) {
                float w[8];
#pragma unroll
                for (int j = 0; j < 8; ++j)
                    w[j] = W2[(size_t)(ks * 32 + quad * 8 + j) * 64 + nt * 16 + col];
                pack8(w, bh[nt][ks], bl[nt][ks]);
            }
        }
        float b2v[4];
#pragma unroll
        for (int nt = 0; nt < 4; ++nt) b2v[nt] = b2[nt * 16 + col];

        for (int tt = 0; tt < TPW; ++tt) {
            float va[16], ua[PT];
            load_vrows<PT, KP, KREAL>(V, idxa, idxb, tt, lane, va);
            load_urows<PT>(U, base16, tt, lane, ua);

            f32x4 acc[4];
            stage_mfma<KSH>(base, lane, va, ua, bh, bl, acc);

#pragma unroll
            for (int nt = 0; nt < 4; ++nt) {
                float m = fmaxf(fmaxf(acc[nt].x, acc[nt].y), fmaxf(acc[nt].z, acc[nt].w));
                if (KP == 4) {
                    const float z = fmaxf(m + b2v[nt], 0.0f);
                    hw[(tt * 4 + quad) * 68 + nt * 16 + col] = z;
                } else {
                    m = fmaxf(m, __shfl_xor(m, 16));
                    const float z = fmaxf(m + b2v[nt], 0.0f);
                    if ((lane & 16) == 0)
                        hw[(tt * 2 + (lane >> 5)) * 68 + nt * 16 + col] = z;
                }
            }
        }
    }
    __builtin_amdgcn_wave_barrier();
    __builtin_amdgcn_s_waitcnt(0xc07f);   // h rows visible to this wave

    // ---- uv phase: [U'|V'] = h @ [W1n_a|W1n_b] ----------------------------
    v8s ah[2], al[2];
#pragma unroll
    for (int ks = 0; ks < 2; ++ks) {
        float w[8];
        const float4 f0 = *(const float4*)(hw + col * 68 + ks * 32 + quad * 8);
        const float4 f1 = *(const float4*)(hw + col * 68 + ks * 32 + quad * 8 + 4);
        w[0] = f0.x; w[1] = f0.y; w[2] = f0.z; w[3] = f0.w;
        w[4] = f1.x; w[5] = f1.y; w[6] = f1.z; w[7] = f1.w;
        pack8(w, ah[ks], al[ks]);
    }

    float prx[4], pry[4], prz[4];
#pragma unroll
    for (int r2 = 0; r2 < 4; ++r2) {
        const int pt = base16 + quad * 4 + r2;
        prx[r2] = pos[pt * 3 + 0];
        pry[r2] = pos[pt * 3 + 1];
        prz[r2] = pos[pt * 3 + 2];
    }
    float wcx[4], wcy[4], wcz[4], b1v[4];
#pragma unroll
    for (int nt = 0; nt < 4; ++nt) {
        wcx[nt] = W1n[128 * 64 + nt * 16 + col];
        wcy[nt] = W1n[129 * 64 + nt * 16 + col];
        wcz[nt] = W1n[130 * 64 + nt * 16 + col];
        b1v[nt] = b1n[nt * 16 + col];
    }

    for (int half = 1; half >= 0; --half) {
        v8s bh2[4][2], bl2[4][2];
#pragma unroll
        for (int nt = 0; nt < 4; ++nt) {
#pragma unroll
            for (int ks = 0; ks < 2; ++ks) {
                float w[8];
#pragma unroll
                for (int j = 0; j < 8; ++j)
                    w[j] = W1n[(size_t)(half * 64 + ks * 32 + quad * 8 + j) * 64 + nt * 16 + col];
                pack8(w, bh2[nt][ks], bl2[nt][ks]);
            }
        }

        f32x4 acc[4];
#pragma unroll
        for (int nt = 0; nt < 4; ++nt) acc[nt] = (f32x4){0.f, 0.f, 0.f, 0.f};
#pragma unroll
        for (int nt = 0; nt < 4; ++nt) {
#pragma unroll
            for (int ks = 0; ks < 2; ++ks) {
                acc[nt] = __builtin_amdgcn_mfma_f32_16x16x32_bf16(ah[ks], bh2[nt][ks], acc[nt], 0, 0, 0);
                acc[nt] = __builtin_amdgcn_mfma_f32_16x16x32_bf16(ah[ks], bl2[nt][ks], acc[nt], 0, 0, 0);
                acc[nt] = __builtin_amdgcn_mfma_f32_16x16x32_bf16(al[ks], bh2[nt][ks], acc[nt], 0, 0, 0);
            }
        }

        float* outp = half ? Vout : Uout;
#pragma unroll
        for (int nt = 0; nt < 4; ++nt) {
            const float* a = (const float*)&acc[nt];
#pragma unroll
            for (int r2 = 0; r2 < 4; ++r2) {
                float dotp = fmaf(prz[r2], wcz[nt], fmaf(pry[r2], wcy[nt], prx[r2] * wcx[nt]));
                float val = half ? (a[r2] + dotp) : (a[r2] + b1v[nt] - dotp);
                outp[(size_t)(base16 + quad * 4 + r2) * 64 + nt * 16 + col] = val;
            }
        }
    }
}

// ---------------------------------------------------------------------------
// Phase: final edge layer, register pool-max + one atomic per wave.
// ---------------------------------------------------------------------------
__device__ __forceinline__ void edge3_phase(
    const float* __restrict__ U, const float* __restrict__ V,
    const int idxa, const int idxb,
    const float* __restrict__ W2, const float* __restrict__ b2,
    float* __restrict__ pooled,
    char* base, const int lane, const int col, const int quad,
    const int base16, const int g)
{
    constexpr int PT = 4, KP = 4, KREAL = 3, KSH = 2, TPW = 4;

    v8s bh[4][2], bl[4][2];
#pragma unroll
    for (int nt = 0; nt < 4; ++nt) {
#pragma unroll
        for (int ks = 0; ks < 2; ++ks) {
            float w[8];
#pragma unroll
            for (int j = 0; j < 8; ++j)
                w[j] = W2[(size_t)(ks * 32 + quad * 8 + j) * 64 + nt * 16 + col];
            pack8(w, bh[nt][ks], bl[nt][ks]);
        }
    }
    float b2v[4];
#pragma unroll
    for (int nt = 0; nt < 4; ++nt) b2v[nt] = b2[nt * 16 + col];

    float zacc[4] = {0.f, 0.f, 0.f, 0.f};   // relu'd values are >= 0

    for (int tt = 0; tt < TPW; ++tt) {
        float va[16], ua[PT];
        load_vrows<PT, KP, KREAL>(V, idxa, idxb, tt, lane, va);
        load_urows<PT>(U, base16, tt, lane, ua);

        f32x4 acc[4];
        stage_mfma<KSH>(base, lane, va, ua, bh, bl, acc);

#pragma unroll
        for (int nt = 0; nt < 4; ++nt) {
            float m = fmaxf(fmaxf(acc[nt].x, acc[nt].y), fmaxf(acc[nt].z, acc[nt].w));
            zacc[nt] = fmaxf(zacc[nt], fmaxf(m + b2v[nt], 0.0f));
        }
    }

#pragma unroll
    for (int nt = 0; nt < 4; ++nt) {
        float zm = fmaxf(zacc[nt], __shfl_xor(zacc[nt], 16));
        zm = fmaxf(zm, __shfl_xor(zm, 32));
        if (quad == 0) {
            atomicMax((unsigned int*)(pooled + (size_t)g * 64 + nt * 16 + col),
                      __float_as_uint(zm));
        }
    }
}

// ---------------------------------------------------------------------------
// Grid-wide barrier: single-use arrival counter (zeroed by knn6_prep_kernel).
// Safe because all NETBLOCKS blocks are co-resident (2 blocks/CU guaranteed
// by __launch_bounds__(256,2) + 34.8KB LDS).  __threadfence() provides the
// cross-XCD release/acquire cache maintenance (Guideline 16).
// ---------------------------------------------------------------------------
__device__ __forceinline__ void gridbar(unsigned* cnt)
{
    __syncthreads();
    __threadfence();
    if (threadIdx.x == 0) {
        __hip_atomic_fetch_add(cnt, 1u, __ATOMIC_ACQ_REL, __HIP_MEMORY_SCOPE_AGENT);
        while (__hip_atomic_load(cnt, __ATOMIC_ACQUIRE, __HIP_MEMORY_SCOPE_AGENT)
               < (unsigned)NETBLOCKS) {
            __builtin_amdgcn_s_sleep(8);
        }
    }
    __syncthreads();
    __threadfence();
}

// ---------------------------------------------------------------------------
// Kernel 2: the whole MFMA pipeline in ONE plain launch (512 blocks).
// Each block runs 2 virtual slots (vb, vb+512) per phase; vb and vb+512 map
// to the same graph & XCD slot -> L2 locality preserved across phases.
// ---------------------------------------------------------------------------
__global__ __launch_bounds__(256, 2) void net_kernel(
    const float* __restrict__ pos, const int* __restrict__ idx,
    float* __restrict__ D, float* __restrict__ C,
    float* __restrict__ A, float* __restrict__ E,
    float* __restrict__ pooled,
    const float* __restrict__ c1W2, const float* __restrict__ c1b2,
    const float* __restrict__ c2W1, const float* __restrict__ c2b1,
    const float* __restrict__ c2W2, const float* __restrict__ c2b2,
    const float* __restrict__ c3W1, const float* __restrict__ c3b1,
    const float* __restrict__ c3W2, const float* __restrict__ c3b2,
    const float* __restrict__ regW, const float* __restrict__ regb,
    float* __restrict__ out,
    unsigned* __restrict__ bar)
{
    __shared__ char  stag[4 * 16 * 272];
    __shared__ float hlds[4][16 * 68];
    const int t = threadIdx.x;
    const int lane = t & 63;
    const int wv = __builtin_amdgcn_readfirstlane(t >> 6);
    char* base = &stag[wv * 16 * 272];
    float* hw = &hlds[wv][0];
    const int col = lane & 15;
    const int quad = lane >> 4;

    // phase 1: edge1 + uv2  (D,C -> A,E)
#pragma unroll
    for (int s = 0; s < 2; ++s) {
        const int vb = blockIdx.x + s * NETBLOCKS;
        const int g = (vb & 7) * 8 + ((vb >> 3) & 7);
        const int base16 = g * NP + (vb >> 6) * 64 + wv * 16;
        const int idxa = idx[(size_t)base16 * 6 + lane];
        const int idxb = idx[(size_t)base16 * 6 + 64 + (lane & 31)];
        edge_uv_phase<2, 8, 6>(D, C, idxa, idxb, c1W2, c1b2, c2W1, c2b1, pos,
                               A, E, base, hw, lane, col, quad, base16);
    }
    gridbar(&bar[0]);

    // phase 2: edge2 + uv3  (A,E -> D,C)
#pragma unroll
    for (int s = 0; s < 2; ++s) {
        const int vb = blockIdx.x + s * NETBLOCKS;
        const int g = (vb & 7) * 8 + ((vb >> 3) & 7);
        const int base16 = g * NP + (vb >> 6) * 64 + wv * 16;
        const int idxa = idx[(size_t)base16 * 6 + lane];
        const int idxb = idx[(size_t)base16 * 6 + 64 + (lane & 31)];
        edge_uv_phase<4, 4, 4>(A, E, idxa, idxb, c2W2, c2b2, c3W1, c3b1, pos,
                               D, C, base, hw, lane, col, quad, base16);
    }
    gridbar(&bar[1]);

    // phase 3: edge3 -> atomic max into pooled (zeroed by knn6_prep_kernel)
#pragma unroll
    for (int s = 0; s < 2; ++s) {
        const int vb = blockIdx.x + s * NETBLOCKS;
        const int g = (vb & 7) * 8 + ((vb >> 3) & 7);
        const int base16 = g * NP + (vb >> 6) * 64 + wv * 16;
        const int idxa = idx[(size_t)base16 * 6 + lane];
        const int idxb = idx[(size_t)base16 * 6 + 64 + (lane & 31)];
        edge3_phase(D, C, idxa, idxb, c3W2, c3b2, pooled,
                    base, lane, col, quad, base16, g);
    }
    gridbar(&bar[2]);

    // phase 4: final 64->6 regression (block 0)
    if (blockIdx.x == 0) {
        for (int id = t; id < NB * 6; id += 256) {
            const int b = id / 6;
            const int o = id - b * 6;
            float z = regb[o];
            const float* pb = pooled + (size_t)b * 64;
            for (int c = 0; c < 64; ++c) z = fmaf(pb[c], regW[c * 6 + o], z);
            out[b * 6 + o] = z;
        }
    }
}

// ---------------------------------------------------------------------------
extern "C" void kernel_launch(void* const* d_in, const int* in_sizes, int n_in,
                              void* d_out, int out_size, void* d_ws, size_t ws_size,
                              hipStream_t stream)
{
    (void)in_sizes; (void)n_in; (void)out_size; (void)ws_size;
    const float* pos   = (const float*)d_in[1];
    const float* c1W1  = (const float*)d_in[3];
    const float* c1b1  = (const float*)d_in[4];
    const float* c1W2  = (const float*)d_in[5];
    const float* c1b2  = (const float*)d_in[6];
    const float* c2W1  = (const float*)d_in[7];
    const float* c2b1  = (const float*)d_in[8];
    const float* c2W2  = (const float*)d_in[9];
    const float* c2b2  = (const float*)d_in[10];
    const float* c3W1  = (const float*)d_in[11];
    const float* c3b1  = (const float*)d_in[12];
    const float* c3W2  = (const float*)d_in[13];
    const float* c3b2  = (const float*)d_in[14];
    const float* regW  = (const float*)d_in[15];
    const float* regb  = (const float*)d_in[16];
    float* out = (float*)d_out;

    // workspace: idx | A | C | D | E | pooled | barrier counters
    char* ws = (char*)d_ws;
    int*   idx = (int*)ws;                                    // 1.5 MB
    float* A = (float*)(ws + 1572864);
    float* C = (float*)(ws + 1572864 + 1 * 16777216);
    float* D = (float*)(ws + 1572864 + 2 * 16777216);
    float* E = (float*)(ws + 1572864 + 3 * 16777216);
    float* pooled = (float*)(ws + 1572864 + 4 * 16777216);    // 16 KB
    unsigned* bar = (unsigned*)(ws + 1572864 + 4 * 16777216 + 16384);

    // kNN + layer-1 prep + zero(pooled, bar) in one launch
    knn6_prep_kernel<<<NB * 16, 256, 0, stream>>>(pos, c1W1, c1b1, idx, D, C,
                                                  pooled, bar);

    // whole MFMA pipeline in one plain launch with in-kernel grid barriers
    net_kernel<<<NETBLOCKS, 256, 0, stream>>>(
        pos, idx, D, C, A, E, pooled,
        c1W2, c1b2, c2W1, c2b1, c2W2, c2b2, c3W1, c3b1, c3W2, c3b2,
        regW, regb, out, bar);
}

// Round 7
// 494.494 us; speedup vs baseline: 1.8021x; 1.8021x over previous
//
#include <hip/hip_runtime.h>
#include <cstddef>

#define NB 64
#define NP 1024
#define NPTS (NB * NP)

typedef __attribute__((ext_vector_type(8))) short v8s;
typedef __attribute__((ext_vector_type(4))) float f32x4;

__device__ __forceinline__ float dist2(const float4 pi, const float sqi, const float4 pq) {
    const float dot = fmaf(pi.z, pq.z, fmaf(pi.y, pq.y, pi.x * pq.x));
    return fmaf(-2.0f, dot, sqi + pq.w);
}

__device__ __forceinline__ void pack8(const float* w, v8s& hv, v8s& lv) {
    union { v8s v; unsigned int u[4]; } H, L;
#pragma unroll
    for (int p = 0; p < 4; ++p) {
        unsigned int a = __float_as_uint(w[2 * p]);
        unsigned int b = __float_as_uint(w[2 * p + 1]);
        unsigned int ha = a & 0xffff0000u, hb = b & 0xffff0000u;
        H.u[p] = (ha >> 16) | hb;
        float la = w[2 * p] - __uint_as_float(ha);
        float lb = w[2 * p + 1] - __uint_as_float(hb);
        L.u[p] = (__float_as_uint(la) >> 16) | (__float_as_uint(lb) & 0xffff0000u);
    }
    hv = H.v; lv = L.v;
}

// ---- shared helpers for the edge phases -----------------------------------

// V-rows of one 16-row staging tile; duplicate-k slots reuse the k=0 row.
template <int PT, int KP, int KREAL>
__device__ __forceinline__ void load_vrows(const float* __restrict__ V,
                                           int idxa, int idxb, int tt, int lane,
                                           float vbuf[16])
{
    constexpr int KSH = (KP == 8) ? 3 : 2;
#pragma unroll
    for (int e = 0; e < 16; ++e) {
        const int p = e >> KSH;
        const int k = e & (KP - 1);
        if (k >= KREAL) continue;
        const int li = (tt * PT + p) * 6 + k;
        const int j = (li < 64) ? __builtin_amdgcn_readlane(idxa, li)
                                : __builtin_amdgcn_readlane(idxb, li - 64);
        vbuf[e] = V[(size_t)j * 64 + lane];
    }
#pragma unroll
    for (int e = 0; e < 16; ++e) {
        const int p = e >> KSH;
        const int k = e & (KP - 1);
        if (k >= KREAL) vbuf[e] = vbuf[p << KSH];
    }
}

template <int PT>
__device__ __forceinline__ void load_urows(const float* __restrict__ U, int pb0,
                                           int tt, int lane, float ubuf[PT])
{
#pragma unroll
    for (int p = 0; p < PT; ++p)
        ubuf[p] = U[(size_t)(pb0 + tt * PT + p) * 64 + lane];
}

// pack the 64x64 edge weight matrix into per-lane MFMA B-frags (hi/lo bf16).
__device__ __forceinline__ void pack_w2(const float* __restrict__ W2,
                                        const float* __restrict__ b2,
                                        int col, int quad,
                                        v8s bh[4][2], v8s bl[4][2], float b2v[4])
{
#pragma unroll
    for (int nt = 0; nt < 4; ++nt) {
#pragma unroll
        for (int ks = 0; ks < 2; ++ks) {
            float w[8];
#pragma unroll
            for (int j = 0; j < 8; ++j)
                w[j] = W2[(size_t)(ks * 32 + quad * 8 + j) * 64 + nt * 16 + col];
            pack8(w, bh[nt][ks], bl[nt][ks]);
        }
    }
#pragma unroll
    for (int nt = 0; nt < 4; ++nt) b2v[nt] = b2[nt * 16 + col];
}

// stage relu(u+v) hi/lo bf16 rows into wave-private LDS, then 24 MFMA.
template <int KSH>
__device__ __forceinline__ void stage_mfma(char* base, int lane,
                                           const float vbuf[16], const float ubuf[],
                                           const v8s bh[4][2], const v8s bl[4][2],
                                           f32x4 acc[4])
{
#pragma unroll
    for (int e = 0; e < 16; ++e) {
        const int p = e >> KSH;
        float tv = ubuf[p] + vbuf[e];
        tv = fmaxf(tv, 0.0f);
        const unsigned int tu = __float_as_uint(tv);
        const unsigned int hi = tu & 0xffff0000u;
        const float lo = tv - __uint_as_float(hi);
        *((short*)(base + e * 272) + lane)       = (short)(hi >> 16);
        *((short*)(base + e * 272 + 128) + lane) = (short)(__float_as_uint(lo) >> 16);
    }
    __builtin_amdgcn_wave_barrier();
    __builtin_amdgcn_s_waitcnt(0xc07f);   // lgkmcnt(0): ds_writes visible

    v8s ah[2], al[2];
#pragma unroll
    for (int ks = 0; ks < 2; ++ks) {
        ah[ks] = *(const v8s*)(base + (lane & 15) * 272 + ks * 64 + (lane >> 4) * 16);
        al[ks] = *(const v8s*)(base + (lane & 15) * 272 + 128 + ks * 64 + (lane >> 4) * 16);
    }
#pragma unroll
    for (int nt = 0; nt < 4; ++nt) acc[nt] = (f32x4){0.f, 0.f, 0.f, 0.f};
#pragma unroll
    for (int nt = 0; nt < 4; ++nt) {
#pragma unroll
        for (int ks = 0; ks < 2; ++ks) {
            acc[nt] = __builtin_amdgcn_mfma_f32_16x16x32_bf16(ah[ks], bh[nt][ks], acc[nt], 0, 0, 0);
            acc[nt] = __builtin_amdgcn_mfma_f32_16x16x32_bf16(ah[ks], bl[nt][ks], acc[nt], 0, 0, 0);
            acc[nt] = __builtin_amdgcn_mfma_f32_16x16x32_bf16(al[ks], bh[nt][ks], acc[nt], 0, 0, 0);
        }
    }
}

// ---------------------------------------------------------------------------
// Kernel 1: proven top-6 kNN + fused layer-1 prep tail (round-5 verified).
// ---------------------------------------------------------------------------
__global__ __launch_bounds__(256) void knn6_prep_kernel(
    const float* __restrict__ pos,
    const float* __restrict__ W1, const float* __restrict__ b1,
    int* __restrict__ idx,
    float* __restrict__ Uout, float* __restrict__ Vout)
{
    __shared__ float4 pts[NP];
    __shared__ float  sd[256 * 4];
    __shared__ float  thr[64];
    __shared__ int    ci[256 * 8];
    __shared__ int    cn[256];

    const int blk = blockIdx.x;
    const int b = blk >> 4;
    const int chunk = blk & 15;
    const int t = threadIdx.x;
    const float* gp = pos + (size_t)b * NP * 3;
    for (int q = t; q < NP; q += 256) {
        float x = gp[q * 3 + 0], y = gp[q * 3 + 1], z = gp[q * 3 + 2];
        pts[q] = make_float4(x, y, z, x * x + y * y + z * z);
    }
    __syncthreads();

    const int p = t >> 2;
    const int sub = t & 3;
    const int il = chunk * 64 + p;
    const float4 pi = pts[il];
    const float sqi = pi.w;

    float d0 = 1e30f, d1 = 1e30f, d2v = 1e30f, d3 = 1e30f;
#pragma unroll 4
    for (int it = 0; it < 256; ++it) {
        const int q = (it << 2) | sub;
        const float dq = dist2(pi, sqi, pts[q]);
        d3  = __builtin_amdgcn_fmed3f(dq, d2v, d3);
        d2v = __builtin_amdgcn_fmed3f(dq, d1, d2v);
        d1  = __builtin_amdgcn_fmed3f(dq, d0, d1);
        d0  = fminf(dq, d0);
    }
    {
        float* sp = &sd[t * 4];
        sp[0] = d0; sp[1] = d1; sp[2] = d2v; sp[3] = d3;
    }
    __syncthreads();

    if (t < 64) {
        float e0 = 1e30f, e1 = 1e30f, e2 = 1e30f, e3 = 1e30f, e4 = 1e30f, e5 = 1e30f;
#pragma unroll
        for (int s = 0; s < 4; ++s) {
            const float* q4 = &sd[(t * 4 + s) * 4];
#pragma unroll
            for (int k = 0; k < 4; ++k) {
                const float d = q4[k];
                e5 = __builtin_amdgcn_fmed3f(d, e4, e5);
                e4 = __builtin_amdgcn_fmed3f(d, e3, e4);
                e3 = __builtin_amdgcn_fmed3f(d, e2, e3);
                e2 = __builtin_amdgcn_fmed3f(d, e1, e2);
                e1 = __builtin_amdgcn_fmed3f(d, e0, e1);
                e0 = fminf(d, e0);
            }
        }
        thr[t] = e5;
    }
    __syncthreads();

    const float th = thr[p];
    int cnt = 0;
#pragma unroll 4
    for (int it = 0; it < 256; ++it) {
        const int q = (it << 2) | sub;
        const float dq = dist2(pi, sqi, pts[q]);
        if (dq <= th) {
            ci[t * 8 + (cnt & 7)] = q;
            ++cnt;
        }
    }
    cn[t] = (cnt > 8) ? 8 : cnt;
    __syncthreads();

    if (t < 64) {
        const float4 pit = pts[chunk * 64 + t];
        const float sqit = pit.w;
        float e0 = 1e30f, e1 = 1e30f, e2 = 1e30f, e3 = 1e30f, e4 = 1e30f, e5 = 1e30f;
        int j0 = 0x7fffffff, j1 = 0x7fffffff, j2 = 0x7fffffff,
            j3 = 0x7fffffff, j4 = 0x7fffffff, j5 = 0x7fffffff;
#pragma unroll
        for (int s = 0; s < 4; ++s) {
            const int tid = t * 4 + s;
            const int n = cn[tid];
            for (int e = 0; e < n; ++e) {
                const int q = ci[tid * 8 + e];
                const float d = dist2(pit, sqit, pts[q]);
                if (d < e5 || (d == e5 && q < j5)) {
                    if (d < e4 || (d == e4 && q < j4)) {
                        e5 = e4; j5 = j4;
                        if (d < e3 || (d == e3 && q < j3)) {
                            e4 = e3; j4 = j3;
                            if (d < e2 || (d == e2 && q < j2)) {
                                e3 = e2; j3 = j2;
                                if (d < e1 || (d == e1 && q < j1)) {
                                    e2 = e1; j2 = j1;
                                    if (d < e0 || (d == e0 && q < j0)) {
                                        e1 = e0; j1 = j0; e0 = d; j0 = q;
                                    } else { e1 = d; j1 = q; }
                                } else { e2 = d; j2 = q; }
                            } else { e3 = d; j3 = q; }
                        } else { e4 = d; j4 = q; }
                    } else { e5 = d; j5 = q; }
                }
            }
        }
        const int gb = b * NP;
        int* op = idx + (size_t)(gb + chunk * 64 + t) * 6;
        op[0] = gb + j0; op[1] = gb + j1; op[2] = gb + j2;
        op[3] = gb + j3; op[4] = gb + j4; op[5] = gb + j5;
    }

    // ---- fused prep tail: 64 points x 64 channels (16 per thread) ---------
    {
        const int p2 = t >> 2;
        const int cb = (t & 3) * 16;
        const int il2 = chunk * 64 + p2;
        const float4 pp = pts[il2];
        const size_t gi = (size_t)(b * NP + il2) * 64;
#pragma unroll
        for (int cc = 0; cc < 16; ++cc) {
            const int c = cb + cc;
            float u = b1[c];
            u = fmaf(pp.x, W1[0 * 64 + c] - W1[6 * 64 + c], u);
            u = fmaf(pp.y, W1[1 * 64 + c] - W1[7 * 64 + c], u);
            u = fmaf(pp.z, W1[2 * 64 + c] - W1[8 * 64 + c], u);
            Uout[gi + c] = u;
            float v =      pp.x * (W1[3 * 64 + c] + W1[6 * 64 + c]);
            v = fmaf(pp.y, W1[4 * 64 + c] + W1[7 * 64 + c], v);
            v = fmaf(pp.z, W1[5 * 64 + c] + W1[8 * 64 + c], v);
            Vout[gi + c] = v;
        }
    }
}

// ---------------------------------------------------------------------------
// Phase: fused edge(N) + uv(N+1) for ONE 16-point group (round-5 verified
// math; W2 edge frags passed in, packed once per layer by the caller).
// ---------------------------------------------------------------------------
template <int PT, int KP, int KREAL>
__device__ __forceinline__ void edge_uv_phase(
    const float* __restrict__ U, const float* __restrict__ V,
    const int idxa, const int idxb,
    const v8s bh[4][2], const v8s bl[4][2], const float b2v[4],
    const float* __restrict__ W1n, const float* __restrict__ b1n,
    const float* __restrict__ pos,
    float* __restrict__ Uout, float* __restrict__ Vout,
    char* base, float* hw, const int lane, const int col, const int quad,
    const int base16)
{
    constexpr int KSH = (KP == 8) ? 3 : 2;
    constexpr int TPW = 16 / PT;

    // ---- edge: fill this group's 16 h rows --------------------------------
    for (int tt = 0; tt < TPW; ++tt) {
        float va[16], ua[PT];
        load_vrows<PT, KP, KREAL>(V, idxa, idxb, tt, lane, va);
        load_urows<PT>(U, base16, tt, lane, ua);

        f32x4 acc[4];
        stage_mfma<KSH>(base, lane, va, ua, bh, bl, acc);

#pragma unroll
        for (int nt = 0; nt < 4; ++nt) {
            float m = fmaxf(fmaxf(acc[nt].x, acc[nt].y), fmaxf(acc[nt].z, acc[nt].w));
            if (KP == 4) {
                const float z = fmaxf(m + b2v[nt], 0.0f);
                hw[(tt * 4 + quad) * 68 + nt * 16 + col] = z;
            } else {
                m = fmaxf(m, __shfl_xor(m, 16));
                const float z = fmaxf(m + b2v[nt], 0.0f);
                if ((lane & 16) == 0)
                    hw[(tt * 2 + (lane >> 5)) * 68 + nt * 16 + col] = z;
            }
        }
    }
    __builtin_amdgcn_wave_barrier();
    __builtin_amdgcn_s_waitcnt(0xc07f);   // h rows visible to this wave

    // ---- uv: [U'|V'] = h @ [W1n_a|W1n_b] ----------------------------------
    v8s ah[2], al[2];
#pragma unroll
    for (int ks = 0; ks < 2; ++ks) {
        float w[8];
        const float4 f0 = *(const float4*)(hw + col * 68 + ks * 32 + quad * 8);
        const float4 f1 = *(const float4*)(hw + col * 68 + ks * 32 + quad * 8 + 4);
        w[0] = f0.x; w[1] = f0.y; w[2] = f0.z; w[3] = f0.w;
        w[4] = f1.x; w[5] = f1.y; w[6] = f1.z; w[7] = f1.w;
        pack8(w, ah[ks], al[ks]);
    }

    float prx[4], pry[4], prz[4];
#pragma unroll
    for (int r2 = 0; r2 < 4; ++r2) {
        const int pt = base16 + quad * 4 + r2;
        prx[r2] = pos[pt * 3 + 0];
        pry[r2] = pos[pt * 3 + 1];
        prz[r2] = pos[pt * 3 + 2];
    }
    float wcx[4], wcy[4], wcz[4], b1v[4];
#pragma unroll
    for (int nt = 0; nt < 4; ++nt) {
        wcx[nt] = W1n[128 * 64 + nt * 16 + col];
        wcy[nt] = W1n[129 * 64 + nt * 16 + col];
        wcz[nt] = W1n[130 * 64 + nt * 16 + col];
        b1v[nt] = b1n[nt * 16 + col];
    }

    for (int half = 1; half >= 0; --half) {
        v8s bh2[4][2], bl2[4][2];
#pragma unroll
        for (int nt = 0; nt < 4; ++nt) {
#pragma unroll
            for (int ks = 0; ks < 2; ++ks) {
                float w[8];
#pragma unroll
                for (int j = 0; j < 8; ++j)
                    w[j] = W1n[(size_t)(half * 64 + ks * 32 + quad * 8 + j) * 64 + nt * 16 + col];
                pack8(w, bh2[nt][ks], bl2[nt][ks]);
            }
        }

        f32x4 acc[4];
#pragma unroll
        for (int nt = 0; nt < 4; ++nt) acc[nt] = (f32x4){0.f, 0.f, 0.f, 0.f};
#pragma unroll
        for (int nt = 0; nt < 4; ++nt) {
#pragma unroll
            for (int ks = 0; ks < 2; ++ks) {
                acc[nt] = __builtin_amdgcn_mfma_f32_16x16x32_bf16(ah[ks], bh2[nt][ks], acc[nt], 0, 0, 0);
                acc[nt] = __builtin_amdgcn_mfma_f32_16x16x32_bf16(ah[ks], bl2[nt][ks], acc[nt], 0, 0, 0);
                acc[nt] = __builtin_amdgcn_mfma_f32_16x16x32_bf16(al[ks], bh2[nt][ks], acc[nt], 0, 0, 0);
            }
        }

        float* outp = half ? Vout : Uout;
#pragma unroll
        for (int nt = 0; nt < 4; ++nt) {
            const float* a = (const float*)&acc[nt];
#pragma unroll
            for (int r2 = 0; r2 < 4; ++r2) {
                float dotp = fmaf(prz[r2], wcz[nt], fmaf(pry[r2], wcy[nt], prx[r2] * wcx[nt]));
                float val = half ? (a[r2] + dotp) : (a[r2] + b1v[nt] - dotp);
                outp[(size_t)(base16 + quad * 4 + r2) * 64 + nt * 16 + col] = val;
            }
        }
    }
}

// ---------------------------------------------------------------------------
// Kernel 2 (mega): one block per graph runs the WHOLE MFMA pipeline.
// All gathers are intra-graph -> intra-block: only __syncthreads() between
// layers (same CU, L1-coherent).  No grid barriers, no fences, no atomics,
// no pooled buffer, no reg kernel.  Per-16-point-group math is verbatim the
// round-5 verified device code -> bit-identical output.
// ---------------------------------------------------------------------------
__global__ __launch_bounds__(256) void mega_kernel(
    const float* __restrict__ pos, const int* __restrict__ idx,
    float* __restrict__ D, float* __restrict__ C,
    float* __restrict__ A, float* __restrict__ E,
    const float* __restrict__ c1W2, const float* __restrict__ c1b2,
    const float* __restrict__ c2W1, const float* __restrict__ c2b1,
    const float* __restrict__ c2W2, const float* __restrict__ c2b2,
    const float* __restrict__ c3W1, const float* __restrict__ c3b1,
    const float* __restrict__ c3W2, const float* __restrict__ c3b2,
    const float* __restrict__ regW, const float* __restrict__ regb,
    float* __restrict__ out)
{
    __shared__ char  stag[4 * 16 * 272];
    __shared__ float hlds[4][16 * 68];
    __shared__ float pool[64];
    const int t = threadIdx.x;
    const int lane = t & 63;
    const int wv = __builtin_amdgcn_readfirstlane(t >> 6);
    char* base = &stag[wv * 16 * 272];
    float* hw = &hlds[wv][0];
    const int col = lane & 15;
    const int quad = lane >> 4;
    const int g = blockIdx.x;            // one graph per block

    // ---- layer 1: edge1 + uv2  (D,C -> A,E) -------------------------------
    {
        v8s bh[4][2], bl[4][2]; float b2v[4];
        pack_w2(c1W2, c1b2, col, quad, bh, bl, b2v);
        for (int grp = 0; grp < 16; ++grp) {
            const int base16 = g * NP + grp * 64 + wv * 16;
            const int idxa = idx[(size_t)base16 * 6 + lane];
            const int idxb = idx[(size_t)base16 * 6 + 64 + (lane & 31)];
            edge_uv_phase<2, 8, 6>(D, C, idxa, idxb, bh, bl, b2v,
                                   c2W1, c2b1, pos, A, E,
                                   base, hw, lane, col, quad, base16);
        }
    }
    __threadfence_block();
    __syncthreads();

    // ---- layer 2: edge2 + uv3  (A,E -> D,C) -------------------------------
    {
        v8s bh[4][2], bl[4][2]; float b2v[4];
        pack_w2(c2W2, c2b2, col, quad, bh, bl, b2v);
        for (int grp = 0; grp < 16; ++grp) {
            const int base16 = g * NP + grp * 64 + wv * 16;
            const int idxa = idx[(size_t)base16 * 6 + lane];
            const int idxb = idx[(size_t)base16 * 6 + 64 + (lane & 31)];
            edge_uv_phase<4, 4, 4>(A, E, idxa, idxb, bh, bl, b2v,
                                   c3W1, c3b1, pos, D, C,
                                   base, hw, lane, col, quad, base16);
        }
    }
    __threadfence_block();
    __syncthreads();

    // ---- layer 3: edge3 -> per-wave max, block-reduce, regression ---------
    {
        v8s bh[4][2], bl[4][2]; float b2v[4];
        pack_w2(c3W2, c3b2, col, quad, bh, bl, b2v);

        float zacc[4] = {0.f, 0.f, 0.f, 0.f};   // relu'd values >= 0
        for (int u = 0; u < 32; ++u) {
            const int pbase = g * NP + (u * 4 + wv) * 8;   // 8 consecutive pts
            const int idxa = idx[(size_t)pbase * 6 + lane];
            for (int tt = 0; tt < 2; ++tt) {
                float va[16], ua[4];
                load_vrows<4, 4, 3>(C, idxa, idxa, tt, lane, va);
                load_urows<4>(D, pbase, tt, lane, ua);
                f32x4 acc[4];
                stage_mfma<2>(base, lane, va, ua, bh, bl, acc);
#pragma unroll
                for (int nt = 0; nt < 4; ++nt) {
                    float m = fmaxf(fmaxf(acc[nt].x, acc[nt].y),
                                    fmaxf(acc[nt].z, acc[nt].w));
                    zacc[nt] = fmaxf(zacc[nt], fmaxf(m + b2v[nt], 0.0f));
                }
            }
        }
#pragma unroll
        for (int nt = 0; nt < 4; ++nt) {
            float zm = fmaxf(zacc[nt], __shfl_xor(zacc[nt], 16));
            zm = fmaxf(zm, __shfl_xor(zm, 32));
            if (quad == 0) hlds[wv][nt * 16 + col] = zm;
        }
    }
    __syncthreads();

    if (t < 64)
        pool[t] = fmaxf(fmaxf(hlds[0][t], hlds[1][t]),
                        fmaxf(hlds[2][t], hlds[3][t]));
    __syncthreads();

    if (t < 6) {
        float z = regb[t];
        for (int c = 0; c < 64; ++c) z = fmaf(pool[c], regW[c * 6 + t], z);
        out[g * 6 + t] = z;
    }
}

// ---------------------------------------------------------------------------
extern "C" void kernel_launch(void* const* d_in, const int* in_sizes, int n_in,
                              void* d_out, int out_size, void* d_ws, size_t ws_size,
                              hipStream_t stream)
{
    (void)in_sizes; (void)n_in; (void)out_size; (void)ws_size;
    const float* pos   = (const float*)d_in[1];
    const float* c1W1  = (const float*)d_in[3];
    const float* c1b1  = (const float*)d_in[4];
    const float* c1W2  = (const float*)d_in[5];
    const float* c1b2  = (const float*)d_in[6];
    const float* c2W1  = (const float*)d_in[7];
    const float* c2b1  = (const float*)d_in[8];
    const float* c2W2  = (const float*)d_in[9];
    const float* c2b2  = (const float*)d_in[10];
    const float* c3W1  = (const float*)d_in[11];
    const float* c3b1  = (const float*)d_in[12];
    const float* c3W2  = (const float*)d_in[13];
    const float* c3b2  = (const float*)d_in[14];
    const float* regW  = (const float*)d_in[15];
    const float* regb  = (const float*)d_in[16];
    float* out = (float*)d_out;

    // workspace: idx | A | C | D | E   (A,C,D,E are 65536x64 fp32)
    char* ws = (char*)d_ws;
    int*   idx = (int*)ws;                                    // 1.5 MB
    float* A = (float*)(ws + 1572864);
    float* C = (float*)(ws + 1572864 + 1 * 16777216);
    float* D = (float*)(ws + 1572864 + 2 * 16777216);
    float* E = (float*)(ws + 1572864 + 3 * 16777216);

    // kNN + layer-1 prep (U1 -> D, Vpos -> C) in one launch
    knn6_prep_kernel<<<NB * 16, 256, 0, stream>>>(pos, c1W1, c1b1, idx, D, C);

    // entire MFMA pipeline + pooling + regression: one block per graph
    mega_kernel<<<NB, 256, 0, stream>>>(
        pos, idx, D, C, A, E,
        c1W2, c1b2, c2W1, c2b1, c2W2, c2b2, c3W1, c3b1, c3W2, c3b2,
        regW, regb, out);
}

// Round 8
// 215.121 us; speedup vs baseline: 4.1424x; 2.2987x over previous
//
#include <hip/hip_runtime.h>
#include <cstddef>

#define NB 64
#define NP 1024
#define NPTS (NB * NP)

typedef __attribute__((ext_vector_type(8))) short v8s;
typedef __attribute__((ext_vector_type(4))) float f32x4;

__device__ __forceinline__ float dist2(const float4 pi, const float sqi, const float4 pq) {
    const float dot = fmaf(pi.z, pq.z, fmaf(pi.y, pq.y, pi.x * pq.x));
    return fmaf(-2.0f, dot, sqi + pq.w);
}

__device__ __forceinline__ void pack8(const float* w, v8s& hv, v8s& lv) {
    union { v8s v; unsigned int u[4]; } H, L;
#pragma unroll
    for (int p = 0; p < 4; ++p) {
        unsigned int a = __float_as_uint(w[2 * p]);
        unsigned int b = __float_as_uint(w[2 * p + 1]);
        unsigned int ha = a & 0xffff0000u, hb = b & 0xffff0000u;
        H.u[p] = (ha >> 16) | hb;
        float la = w[2 * p] - __uint_as_float(ha);
        float lb = w[2 * p + 1] - __uint_as_float(hb);
        L.u[p] = (__float_as_uint(la) >> 16) | (__float_as_uint(lb) & 0xffff0000u);
    }
    hv = H.v; lv = L.v;
}

// ---- shared helpers for the edge kernels ----------------------------------

// V-rows of one 16-row staging tile; duplicate-k slots reuse the k=0 row.
template <int PT, int KP, int KREAL>
__device__ __forceinline__ void load_vrows(const float* __restrict__ V,
                                           int idxa, int idxb, int tt, int lane,
                                           float vbuf[16])
{
    constexpr int KSH = (KP == 8) ? 3 : 2;
#pragma unroll
    for (int e = 0; e < 16; ++e) {
        const int p = e >> KSH;
        const int k = e & (KP - 1);
        if (k >= KREAL) continue;
        const int li = (tt * PT + p) * 6 + k;
        const int j = (li < 64) ? __builtin_amdgcn_readlane(idxa, li)
                                : __builtin_amdgcn_readlane(idxb, li - 64);
        vbuf[e] = V[(size_t)j * 64 + lane];
    }
#pragma unroll
    for (int e = 0; e < 16; ++e) {
        const int p = e >> KSH;
        const int k = e & (KP - 1);
        if (k >= KREAL) vbuf[e] = vbuf[p << KSH];
    }
}

template <int PT>
__device__ __forceinline__ void load_urows(const float* __restrict__ U, int pb0,
                                           int tt, int lane, float ubuf[PT])
{
#pragma unroll
    for (int p = 0; p < PT; ++p)
        ubuf[p] = U[(size_t)(pb0 + tt * PT + p) * 64 + lane];
}

// stage relu(u+v) hi/lo bf16 rows into wave-private LDS, then 24 MFMA.
template <int KSH>
__device__ __forceinline__ void stage_mfma(char* base, int lane,
                                           const float vbuf[16], const float ubuf[],
                                           const v8s bh[4][2], const v8s bl[4][2],
                                           f32x4 acc[4])
{
#pragma unroll
    for (int e = 0; e < 16; ++e) {
        const int p = e >> KSH;
        float tv = ubuf[p] + vbuf[e];
        tv = fmaxf(tv, 0.0f);
        const unsigned int tu = __float_as_uint(tv);
        const unsigned int hi = tu & 0xffff0000u;
        const float lo = tv - __uint_as_float(hi);
        *((short*)(base + e * 272) + lane)       = (short)(hi >> 16);
        *((short*)(base + e * 272 + 128) + lane) = (short)(__float_as_uint(lo) >> 16);
    }
    __builtin_amdgcn_wave_barrier();
    __builtin_amdgcn_s_waitcnt(0xc07f);   // lgkmcnt(0): ds_writes visible

    v8s ah[2], al[2];
#pragma unroll
    for (int ks = 0; ks < 2; ++ks) {
        ah[ks] = *(const v8s*)(base + (lane & 15) * 272 + ks * 64 + (lane >> 4) * 16);
        al[ks] = *(const v8s*)(base + (lane & 15) * 272 + 128 + ks * 64 + (lane >> 4) * 16);
    }
#pragma unroll
    for (int nt = 0; nt < 4; ++nt) acc[nt] = (f32x4){0.f, 0.f, 0.f, 0.f};
#pragma unroll
    for (int nt = 0; nt < 4; ++nt) {
#pragma unroll
        for (int ks = 0; ks < 2; ++ks) {
            acc[nt] = __builtin_amdgcn_mfma_f32_16x16x32_bf16(ah[ks], bh[nt][ks], acc[nt], 0, 0, 0);
            acc[nt] = __builtin_amdgcn_mfma_f32_16x16x32_bf16(ah[ks], bl[nt][ks], acc[nt], 0, 0, 0);
            acc[nt] = __builtin_amdgcn_mfma_f32_16x16x32_bf16(al[ks], bh[nt][ks], acc[nt], 0, 0, 0);
        }
    }
}

// ---------------------------------------------------------------------------
// Kernel 1: proven top-6 kNN + fused layer-1 prep tail (round-5 verified).
// ---------------------------------------------------------------------------
__global__ __launch_bounds__(256) void knn6_prep_kernel(
    const float* __restrict__ pos,
    const float* __restrict__ W1, const float* __restrict__ b1,
    int* __restrict__ idx,
    float* __restrict__ Uout, float* __restrict__ Vout)
{
    __shared__ float4 pts[NP];
    __shared__ float  sd[256 * 4];
    __shared__ float  thr[64];
    __shared__ int    ci[256 * 8];
    __shared__ int    cn[256];

    const int blk = blockIdx.x;
    const int b = blk >> 4;
    const int chunk = blk & 15;
    const int t = threadIdx.x;
    const float* gp = pos + (size_t)b * NP * 3;
    for (int q = t; q < NP; q += 256) {
        float x = gp[q * 3 + 0], y = gp[q * 3 + 1], z = gp[q * 3 + 2];
        pts[q] = make_float4(x, y, z, x * x + y * y + z * z);
    }
    __syncthreads();

    const int p = t >> 2;
    const int sub = t & 3;
    const int il = chunk * 64 + p;
    const float4 pi = pts[il];
    const float sqi = pi.w;

    float d0 = 1e30f, d1 = 1e30f, d2v = 1e30f, d3 = 1e30f;
#pragma unroll 4
    for (int it = 0; it < 256; ++it) {
        const int q = (it << 2) | sub;
        const float dq = dist2(pi, sqi, pts[q]);
        d3  = __builtin_amdgcn_fmed3f(dq, d2v, d3);
        d2v = __builtin_amdgcn_fmed3f(dq, d1, d2v);
        d1  = __builtin_amdgcn_fmed3f(dq, d0, d1);
        d0  = fminf(dq, d0);
    }
    {
        float* sp = &sd[t * 4];
        sp[0] = d0; sp[1] = d1; sp[2] = d2v; sp[3] = d3;
    }
    __syncthreads();

    if (t < 64) {
        float e0 = 1e30f, e1 = 1e30f, e2 = 1e30f, e3 = 1e30f, e4 = 1e30f, e5 = 1e30f;
#pragma unroll
        for (int s = 0; s < 4; ++s) {
            const float* q4 = &sd[(t * 4 + s) * 4];
#pragma unroll
            for (int k = 0; k < 4; ++k) {
                const float d = q4[k];
                e5 = __builtin_amdgcn_fmed3f(d, e4, e5);
                e4 = __builtin_amdgcn_fmed3f(d, e3, e4);
                e3 = __builtin_amdgcn_fmed3f(d, e2, e3);
                e2 = __builtin_amdgcn_fmed3f(d, e1, e2);
                e1 = __builtin_amdgcn_fmed3f(d, e0, e1);
                e0 = fminf(d, e0);
            }
        }
        thr[t] = e5;
    }
    __syncthreads();

    const float th = thr[p];
    int cnt = 0;
#pragma unroll 4
    for (int it = 0; it < 256; ++it) {
        const int q = (it << 2) | sub;
        const float dq = dist2(pi, sqi, pts[q]);
        if (dq <= th) {
            ci[t * 8 + (cnt & 7)] = q;
            ++cnt;
        }
    }
    cn[t] = (cnt > 8) ? 8 : cnt;
    __syncthreads();

    if (t < 64) {
        const float4 pit = pts[chunk * 64 + t];
        const float sqit = pit.w;
        float e0 = 1e30f, e1 = 1e30f, e2 = 1e30f, e3 = 1e30f, e4 = 1e30f, e5 = 1e30f;
        int j0 = 0x7fffffff, j1 = 0x7fffffff, j2 = 0x7fffffff,
            j3 = 0x7fffffff, j4 = 0x7fffffff, j5 = 0x7fffffff;
#pragma unroll
        for (int s = 0; s < 4; ++s) {
            const int tid = t * 4 + s;
            const int n = cn[tid];
            for (int e = 0; e < n; ++e) {
                const int q = ci[tid * 8 + e];
                const float d = dist2(pit, sqit, pts[q]);
                if (d < e5 || (d == e5 && q < j5)) {
                    if (d < e4 || (d == e4 && q < j4)) {
                        e5 = e4; j5 = j4;
                        if (d < e3 || (d == e3 && q < j3)) {
                            e4 = e3; j4 = j3;
                            if (d < e2 || (d == e2 && q < j2)) {
                                e3 = e2; j3 = j2;
                                if (d < e1 || (d == e1 && q < j1)) {
                                    e2 = e1; j2 = j1;
                                    if (d < e0 || (d == e0 && q < j0)) {
                                        e1 = e0; j1 = j0; e0 = d; j0 = q;
                                    } else { e1 = d; j1 = q; }
                                } else { e2 = d; j2 = q; }
                            } else { e3 = d; j3 = q; }
                        } else { e4 = d; j4 = q; }
                    } else { e5 = d; j5 = q; }
                }
            }
        }
        const int gb = b * NP;
        int* op = idx + (size_t)(gb + chunk * 64 + t) * 6;
        op[0] = gb + j0; op[1] = gb + j1; op[2] = gb + j2;
        op[3] = gb + j3; op[4] = gb + j4; op[5] = gb + j5;
    }

    // ---- fused prep tail: 64 points x 64 channels (16 per thread) ---------
    {
        const int p2 = t >> 2;
        const int cb = (t & 3) * 16;
        const int il2 = chunk * 64 + p2;
        const float4 pp = pts[il2];
        const size_t gi = (size_t)(b * NP + il2) * 64;
#pragma unroll
        for (int cc = 0; cc < 16; ++cc) {
            const int c = cb + cc;
            float u = b1[c];
            u = fmaf(pp.x, W1[0 * 64 + c] - W1[6 * 64 + c], u);
            u = fmaf(pp.y, W1[1 * 64 + c] - W1[7 * 64 + c], u);
            u = fmaf(pp.z, W1[2 * 64 + c] - W1[8 * 64 + c], u);
            Uout[gi + c] = u;
            float v =      pp.x * (W1[3 * 64 + c] + W1[6 * 64 + c]);
            v = fmaf(pp.y, W1[4 * 64 + c] + W1[7 * 64 + c], v);
            v = fmaf(pp.z, W1[5 * 64 + c] + W1[8 * 64 + c], v);
            Vout[gi + c] = v;
        }
    }
}

// ---------------------------------------------------------------------------
// Kernel 2: FUSED edge(N) + uv(N+1).  Single-buffered (dbuf was neutral),
// __launch_bounds__(256,4) caps VGPR at 128 -> 4 blocks/CU co-resident with
// the 34.8KB LDS -> 4 waves/SIMD of latency hiding (was 2-3 at ~150-220 VGPR).
// ---------------------------------------------------------------------------
template <int PT, int KP, int KREAL>
__global__ __launch_bounds__(256, 4) void fused_edge_uv_kernel(
    const float* __restrict__ U, const float* __restrict__ V,
    const int* __restrict__ idx,
    const float* __restrict__ W2, const float* __restrict__ b2,
    const float* __restrict__ W1n, const float* __restrict__ b1n,
    const float* __restrict__ pos,
    float* __restrict__ Uout, float* __restrict__ Vout,
    float* __restrict__ pooled_zero)
{
    __shared__ char  stag[4 * 16 * 272];
    __shared__ float hlds[4][16 * 68];
    const int t = threadIdx.x;
    const int lane = t & 63;
    const int wv = __builtin_amdgcn_readfirstlane(t >> 6);
    char* base = &stag[wv * 16 * 272];
    float* hw = &hlds[wv][0];
    const int col = lane & 15;
    const int quad = lane >> 4;
    constexpr int KSH = (KP == 8) ? 3 : 2;
    constexpr int TPW = 16 / PT;

    if (pooled_zero != nullptr && blockIdx.x == 0) {
#pragma unroll
        for (int i = 0; i < 16; ++i) pooled_zero[i * 256 + t] = 0.0f;
    }

    const int x = blockIdx.x & 7;        // XCD slot
    const int r = blockIdx.x >> 3;       // 0..127
    const int g = x * 8 + (r & 7);       // graph
    const int sb = r >> 3;               // 0..15
    const int base16 = g * NP + sb * 64 + wv * 16;   // this wave's 16 points

    // preload ALL 96 neighbor indices for this wave (one coalesced load pair)
    const int idxa = idx[(size_t)base16 * 6 + lane];
    const int idxb = idx[(size_t)base16 * 6 + 64 + (lane & 31)];

    // ---- edge phase --------------------------------------------------------
    {
        v8s bh[4][2], bl[4][2];
#pragma unroll
        for (int nt = 0; nt < 4; ++nt) {
#pragma unroll
            for (int ks = 0; ks < 2; ++ks) {
                float w[8];
#pragma unroll
                for (int j = 0; j < 8; ++j)
                    w[j] = W2[(size_t)(ks * 32 + quad * 8 + j) * 64 + nt * 16 + col];
                pack8(w, bh[nt][ks], bl[nt][ks]);
            }
        }
        float b2v[4];
#pragma unroll
        for (int nt = 0; nt < 4; ++nt) b2v[nt] = b2[nt * 16 + col];

        for (int tt = 0; tt < TPW; ++tt) {
            float va[16], ua[PT];
            load_vrows<PT, KP, KREAL>(V, idxa, idxb, tt, lane, va);
            load_urows<PT>(U, base16, tt, lane, ua);

            f32x4 acc[4];
            stage_mfma<KSH>(base, lane, va, ua, bh, bl, acc);

#pragma unroll
            for (int nt = 0; nt < 4; ++nt) {
                float m = fmaxf(fmaxf(acc[nt].x, acc[nt].y), fmaxf(acc[nt].z, acc[nt].w));
                if (KP == 4) {
                    const float z = fmaxf(m + b2v[nt], 0.0f);
                    hw[(tt * 4 + quad) * 68 + nt * 16 + col] = z;
                } else {
                    m = fmaxf(m, __shfl_xor(m, 16));
                    const float z = fmaxf(m + b2v[nt], 0.0f);
                    if ((lane & 16) == 0)
                        hw[(tt * 2 + (lane >> 5)) * 68 + nt * 16 + col] = z;
                }
            }
        }
    }
    __builtin_amdgcn_wave_barrier();
    __builtin_amdgcn_s_waitcnt(0xc07f);   // h rows visible to this wave

    // ---- uv phase: [U'|V'] = h @ [W1n_a|W1n_b] ----------------------------
    v8s ah[2], al[2];
#pragma unroll
    for (int ks = 0; ks < 2; ++ks) {
        float w[8];
        const float4 f0 = *(const float4*)(hw + col * 68 + ks * 32 + quad * 8);
        const float4 f1 = *(const float4*)(hw + col * 68 + ks * 32 + quad * 8 + 4);
        w[0] = f0.x; w[1] = f0.y; w[2] = f0.z; w[3] = f0.w;
        w[4] = f1.x; w[5] = f1.y; w[6] = f1.z; w[7] = f1.w;
        pack8(w, ah[ks], al[ks]);
    }

    float prx[4], pry[4], prz[4];
#pragma unroll
    for (int r2 = 0; r2 < 4; ++r2) {
        const int pt = base16 + quad * 4 + r2;
        prx[r2] = pos[pt * 3 + 0];
        pry[r2] = pos[pt * 3 + 1];
        prz[r2] = pos[pt * 3 + 2];
    }
    float wcx[4], wcy[4], wcz[4], b1v[4];
#pragma unroll
    for (int nt = 0; nt < 4; ++nt) {
        wcx[nt] = W1n[128 * 64 + nt * 16 + col];
        wcy[nt] = W1n[129 * 64 + nt * 16 + col];
        wcz[nt] = W1n[130 * 64 + nt * 16 + col];
        b1v[nt] = b1n[nt * 16 + col];
    }

    for (int half = 1; half >= 0; --half) {
        v8s bh2[4][2], bl2[4][2];
#pragma unroll
        for (int nt = 0; nt < 4; ++nt) {
#pragma unroll
            for (int ks = 0; ks < 2; ++ks) {
                float w[8];
#pragma unroll
                for (int j = 0; j < 8; ++j)
                    w[j] = W1n[(size_t)(half * 64 + ks * 32 + quad * 8 + j) * 64 + nt * 16 + col];
                pack8(w, bh2[nt][ks], bl2[nt][ks]);
            }
        }

        f32x4 acc[4];
#pragma unroll
        for (int nt = 0; nt < 4; ++nt) acc[nt] = (f32x4){0.f, 0.f, 0.f, 0.f};
#pragma unroll
        for (int nt = 0; nt < 4; ++nt) {
#pragma unroll
            for (int ks = 0; ks < 2; ++ks) {
                acc[nt] = __builtin_amdgcn_mfma_f32_16x16x32_bf16(ah[ks], bh2[nt][ks], acc[nt], 0, 0, 0);
                acc[nt] = __builtin_amdgcn_mfma_f32_16x16x32_bf16(ah[ks], bl2[nt][ks], acc[nt], 0, 0, 0);
                acc[nt] = __builtin_amdgcn_mfma_f32_16x16x32_bf16(al[ks], bh2[nt][ks], acc[nt], 0, 0, 0);
            }
        }

        float* outp = half ? Vout : Uout;
#pragma unroll
        for (int nt = 0; nt < 4; ++nt) {
            const float* a = (const float*)&acc[nt];
#pragma unroll
            for (int r2 = 0; r2 < 4; ++r2) {
                float dotp = fmaf(prz[r2], wcz[nt], fmaf(pry[r2], wcy[nt], prx[r2] * wcx[nt]));
                float val = half ? (a[r2] + dotp) : (a[r2] + b1v[nt] - dotp);
                outp[(size_t)(base16 + quad * 4 + r2) * 64 + nt * 16 + col] = val;
            }
        }
    }
}

// ---------------------------------------------------------------------------
// Kernel 3: final edge layer, single-buffered, pool-max in registers,
// __launch_bounds__(256,4) for occupancy.
// ---------------------------------------------------------------------------
template <int PT, int KP, int KREAL, int TPW>
__global__ __launch_bounds__(256, 4) void edge3_mfma_kernel(
    const float* __restrict__ U, const float* __restrict__ V,
    const int* __restrict__ idx,
    const float* __restrict__ W2, const float* __restrict__ b2,
    float* __restrict__ outp)
{
    __shared__ char ldsbuf[4 * 16 * 272];
    const int t = threadIdx.x;
    const int lane = t & 63;
    const int wv = __builtin_amdgcn_readfirstlane(t >> 6);
    char* base = &ldsbuf[wv * 16 * 272];
    const int col = lane & 15;
    const int quad = lane >> 4;
    constexpr int KSH = (KP == 8) ? 3 : 2;

    const int x = blockIdx.x & 7;
    const int r = blockIdx.x >> 3;
    const int g = x * 8 + (r & 7);
    const int sb = r >> 3;
    const int pbase = g * NP + (sb * 4 + wv) * (PT * TPW);   // 8 consecutive points

    const int idxa = idx[(size_t)pbase * 6 + lane];

    v8s bh[4][2], bl[4][2];
#pragma unroll
    for (int nt = 0; nt < 4; ++nt) {
#pragma unroll
        for (int ks = 0; ks < 2; ++ks) {
            float w[8];
#pragma unroll
            for (int j = 0; j < 8; ++j)
                w[j] = W2[(size_t)(ks * 32 + quad * 8 + j) * 64 + nt * 16 + col];
            pack8(w, bh[nt][ks], bl[nt][ks]);
        }
    }
    float b2v[4];
#pragma unroll
    for (int nt = 0; nt < 4; ++nt) b2v[nt] = b2[nt * 16 + col];

    float zacc[4] = {0.f, 0.f, 0.f, 0.f};   // relu'd values are >= 0

    for (int tt = 0; tt < TPW; ++tt) {
        float va[16], ua[PT];
        load_vrows<PT, KP, KREAL>(V, idxa, idxa, tt, lane, va);
        load_urows<PT>(U, pbase, tt, lane, ua);

        f32x4 acc[4];
        stage_mfma<KSH>(base, lane, va, ua, bh, bl, acc);

#pragma unroll
        for (int nt = 0; nt < 4; ++nt) {
            float m = fmaxf(fmaxf(acc[nt].x, acc[nt].y), fmaxf(acc[nt].z, acc[nt].w));
            zacc[nt] = fmaxf(zacc[nt], fmaxf(m + b2v[nt], 0.0f));
        }
    }

#pragma unroll
    for (int nt = 0; nt < 4; ++nt) {
        float zm = fmaxf(zacc[nt], __shfl_xor(zacc[nt], 16));
        zm = fmaxf(zm, __shfl_xor(zm, 32));
        if (quad == 0) {
            atomicMax((unsigned int*)(outp + (size_t)g * 64 + nt * 16 + col),
                      __float_as_uint(zm));
        }
    }
}

// ---------------------------------------------------------------------------
// Kernel 4: final 64->6 regression from pooled. 6 blocks x 64 threads.
// ---------------------------------------------------------------------------
__global__ __launch_bounds__(64) void reg_kernel(
    const float* __restrict__ pooled, const float* __restrict__ regW,
    const float* __restrict__ regb, float* __restrict__ out)
{
    const int t = blockIdx.x * 64 + threadIdx.x;
    const int b = t / 6;
    const int o = t - b * 6;
    if (t < NB * 6) {
        float z = regb[o];
        const float* pb = pooled + (size_t)b * 64;
        for (int c = 0; c < 64; ++c) z = fmaf(pb[c], regW[c * 6 + o], z);
        out[b * 6 + o] = z;
    }
}

// ---------------------------------------------------------------------------
extern "C" void kernel_launch(void* const* d_in, const int* in_sizes, int n_in,
                              void* d_out, int out_size, void* d_ws, size_t ws_size,
                              hipStream_t stream)
{
    (void)in_sizes; (void)n_in; (void)out_size; (void)ws_size;
    const float* pos   = (const float*)d_in[1];
    const float* c1W1  = (const float*)d_in[3];
    const float* c1b1  = (const float*)d_in[4];
    const float* c1W2  = (const float*)d_in[5];
    const float* c1b2  = (const float*)d_in[6];
    const float* c2W1  = (const float*)d_in[7];
    const float* c2b1  = (const float*)d_in[8];
    const float* c2W2  = (const float*)d_in[9];
    const float* c2b2  = (const float*)d_in[10];
    const float* c3W1  = (const float*)d_in[11];
    const float* c3b1  = (const float*)d_in[12];
    const float* c3W2  = (const float*)d_in[13];
    const float* c3b2  = (const float*)d_in[14];
    const float* regW  = (const float*)d_in[15];
    const float* regb  = (const float*)d_in[16];
    float* out = (float*)d_out;

    // workspace: idx | A | C | D | E | pooled  (A,C,D,E are 65536x64 fp32)
    char* ws = (char*)d_ws;
    int*   idx = (int*)ws;                                    // 1.5 MB
    float* A = (float*)(ws + 1572864);
    float* C = (float*)(ws + 1572864 + 1 * 16777216);
    float* D = (float*)(ws + 1572864 + 2 * 16777216);
    float* E = (float*)(ws + 1572864 + 3 * 16777216);
    float* pooled = (float*)(ws + 1572864 + 4 * 16777216);    // 16 KB

    // kNN + layer-1 prep (U1 -> D, Vpos -> C) in one launch
    knn6_prep_kernel<<<NB * 16, 256, 0, stream>>>(pos, c1W1, c1b1, idx, D, C);

    // fused layer1-edge + layer2-uv: reads (D=U1, C=Vpos) -> U2->A, V2->E
    fused_edge_uv_kernel<2, 8, 6><<<1024, 256, 0, stream>>>(
        D, C, idx, c1W2, c1b2, c2W1, c2b1, pos, A, E, nullptr);

    // fused layer2-edge + layer3-uv: reads (A=U2, E=V2) -> U3->D, V3->C
    // (block 0 zeroes pooled)
    fused_edge_uv_kernel<4, 4, 4><<<1024, 256, 0, stream>>>(
        A, E, idx, c2W2, c2b2, c3W1, c3b1, pos, D, C, pooled);

    // layer3 edge -> atomic max into pooled
    edge3_mfma_kernel<4, 4, 3, 2><<<2048, 256, 0, stream>>>(
        D, C, idx, c3W2, c3b2, pooled);

    // final regression
    reg_kernel<<<6, 64, 0, stream>>>(pooled, regW, regb, out);
}